// Round 2
// baseline (162.899 us; speedup 1.0000x reference)
//
#include <hip/hip_runtime.h>
#include <hip/hip_bf16.h>

#define N_PTS 131072
#define CIN   32
#define COUT  32
#define KNB   27
#define NS    3

typedef __bf16 bf16x8 __attribute__((ext_vector_type(8)));
typedef float  f32x4  __attribute__((ext_vector_type(4)));

// Static device scratch (rewritten deterministically every call).
__device__ __attribute__((aligned(256))) __bf16 g_xT[(size_t)N_PTS * 64];        // [n][b][c] bf16
__device__ __attribute__((aligned(256))) __bf16 g_wp[KNB * NS * COUT * CIN];     // [kc][s][o][c] bf16

// ---------------- pack x: (B,CIN,N) f32 -> (N, B, CIN) bf16 ----------------
__global__ void pack_x(const float* __restrict__ x) {
  int n = blockIdx.x * 256 + threadIdx.x;
  uint u[32];
#pragma unroll
  for (int b = 0; b < 2; ++b)
#pragma unroll
    for (int c = 0; c < 32; c += 2) {
      float f0 = x[(size_t)(b * 32 + c) * N_PTS + n];
      float f1 = x[(size_t)(b * 32 + c + 1) * N_PTS + n];
      union { __bf16 h[2]; uint w; } cv;
      cv.h[0] = (__bf16)f0; cv.h[1] = (__bf16)f1;
      u[b * 16 + c / 2] = cv.w;
    }
  uint4* dst = reinterpret_cast<uint4*>(&g_xT[(size_t)n * 64]);
#pragma unroll
  for (int i = 0; i < 8; ++i)
    dst[i] = make_uint4(u[4 * i], u[4 * i + 1], u[4 * i + 2], u[4 * i + 3]);
}

// ------- pack w: (CIN,S,COUT,27) f32 -> [kc][s][o][c] bf16 (6KB per kc) ----
__global__ void pack_w(const float* __restrict__ w) {
  int e = blockIdx.x * 256 + threadIdx.x;   // 27*3*32*32 = 82944 = 324*256
  int c  = e & 31;
  int o  = (e >> 5) & 31;
  int s  = (e >> 10) % 3;
  int kc = e / 3072;
  g_wp[e] = (__bf16)w[((size_t)(c * NS + s) * COUT + o) * KNB + kc];
}

// ---------------- main GEMM: per block 64 points, all 32 outs --------------
// No in-loop barriers: W fragments read straight from global (L1/L2-hot,
// same addresses across all waves); x gather software-pipelined depth 2.
__global__ __launch_bounds__(256, 4) void aprconv(
    const int* __restrict__ nbr, const int* __restrict__ levels,
    const int* __restrict__ deltas, const float* __restrict__ bias,
    float* __restrict__ out) {

  __shared__ int   s_idx[KNB * 64];          // [kc][p]
  __shared__ int   s_lv[64];
  __shared__ float s_bias[COUT];

  const int tid = threadIdx.x;
  const int n0  = blockIdx.x * 64;
  const int wv  = tid >> 6;
  const int l15 = tid & 15;
  const int lg  = (tid & 63) >> 4;
  const int slot = wv * 16 + l15;

  for (int j = tid; j < 64 * KNB; j += 256) {
    int p = j / KNB, kc = j - p * KNB;
    s_idx[kc * 64 + p] = nbr[(size_t)(n0 + p) * KNB + kc];
  }
  if (tid < 64)   s_lv[tid]   = levels[n0 + tid];
  if (tid < COUT) s_bias[tid] = bias[tid];
  __syncthreads();

  const int d0 = deltas[0], d1 = deltas[1];

  const char* xbase = (const char*)g_xT;
  const char* wlane = (const char*)g_wp + (l15 << 6) + (lg << 4);  // lane offset into a kc-chunk

  f32x4 acc[2][3][2];
#pragma unroll
  for (int b = 0; b < 2; ++b)
#pragma unroll
    for (int s = 0; s < 3; ++s)
#pragma unroll
      for (int ot = 0; ot < 2; ++ot)
        acc[b][s][ot] = (f32x4){0.f, 0.f, 0.f, 0.f};

  // pipeline prologue: x for kc=0 (xa) and kc=1 (xb); W for kc=0 (wa)
  bf16x8 xa0, xa1, xc0, xc1, wa[3][2];
  {
    int i0 = s_idx[slot];
    const char* p0 = xbase + ((uint)i0 << 7) + (lg << 4);
    xa0 = *(const bf16x8*)p0;  xa1 = *(const bf16x8*)(p0 + 64);
    int i1 = s_idx[64 + slot];
    const char* p1 = xbase + ((uint)i1 << 7) + (lg << 4);
    xc0 = *(const bf16x8*)p1;  xc1 = *(const bf16x8*)(p1 + 64);
#pragma unroll
    for (int s = 0; s < 3; ++s)
#pragma unroll
      for (int ot = 0; ot < 2; ++ot)
        wa[s][ot] = *(const bf16x8*)(wlane + (s * 32 + ot * 16) * 64);
  }

#pragma unroll 3
  for (int kc = 0; kc < KNB; ++kc) {
    const int kn1 = (kc + 1 < KNB) ? kc + 1 : KNB - 1;
    const int kn2 = (kc + 2 < KNB) ? kc + 2 : KNB - 1;

    // prefetch W (depth 1) and x (depth 2)
    bf16x8 wn[3][2], xn0, xn1;
    const char* wp = wlane + kn1 * 6144;
#pragma unroll
    for (int s = 0; s < 3; ++s)
#pragma unroll
      for (int ot = 0; ot < 2; ++ot)
        wn[s][ot] = *(const bf16x8*)(wp + (s * 32 + ot * 16) * 64);
    {
      int i2 = s_idx[kn2 * 64 + slot];
      const char* p2 = xbase + ((uint)i2 << 7) + (lg << 4);
      xn0 = *(const bf16x8*)p2;  xn1 = *(const bf16x8*)(p2 + 64);
    }

    // D[o][pt]: A = W (16 outs x 32 ch), B = gathered x (32 ch x 16 pts)
#pragma unroll
    for (int s = 0; s < 3; ++s)
#pragma unroll
      for (int ot = 0; ot < 2; ++ot) {
        acc[0][s][ot] = __builtin_amdgcn_mfma_f32_16x16x32_bf16(wa[s][ot], xa0, acc[0][s][ot], 0, 0, 0);
        acc[1][s][ot] = __builtin_amdgcn_mfma_f32_16x16x32_bf16(wa[s][ot], xa1, acc[1][s][ot], 0, 0, 0);
      }

    // rotate (copies die after unroll)
#pragma unroll
    for (int s = 0; s < 3; ++s)
#pragma unroll
      for (int ot = 0; ot < 2; ++ot)
        wa[s][ot] = wn[s][ot];
    xa0 = xc0; xa1 = xc1; xc0 = xn0; xc1 = xn1;
  }

  // epilogue: per-point s select + bias + store
  // D layout: col(point) = lane&15, row(out) = (lane>>4)*4 + reg
  const int p  = slot;
  const int lv = s_lv[p];
  int e0 = lv + d0; e0 = e0 < 0 ? 0 : (e0 > 2 ? 2 : e0);
  int e1 = lv + d1; e1 = e1 < 0 ? 0 : (e1 > 2 ? 2 : e1);
  const int n = n0 + p;
#pragma unroll
  for (int b = 0; b < 2; ++b) {
    const int sb = b ? e1 : e0;
#pragma unroll
    for (int ot = 0; ot < 2; ++ot) {
      f32x4 a0 = acc[b][0][ot], a1 = acc[b][1][ot], a2 = acc[b][2][ot];
      f32x4 v;
#pragma unroll
      for (int r = 0; r < 4; ++r)
        v[r] = (sb == 0) ? a0[r] : ((sb == 1) ? a1[r] : a2[r]);
#pragma unroll
      for (int r = 0; r < 4; ++r) {
        int o = ot * 16 + lg * 4 + r;
        out[(size_t)(b * COUT + o) * N_PTS + n] = v[r] + s_bias[o];
      }
    }
  }
}

extern "C" void kernel_launch(void* const* d_in, const int* in_sizes, int n_in,
                              void* d_out, int out_size, void* d_ws, size_t ws_size,
                              hipStream_t stream) {
  const float* x    = (const float*)d_in[0];
  const float* w    = (const float*)d_in[1];
  const float* bias = (const float*)d_in[2];
  const int* nbr    = (const int*)d_in[3];
  const int* lv     = (const int*)d_in[4];
  const int* dlt    = (const int*)d_in[5];
  float* out        = (float*)d_out;

  hipLaunchKernelGGL(pack_x, dim3(N_PTS / 256), dim3(256), 0, stream, x);
  hipLaunchKernelGGL(pack_w, dim3((KNB * NS * COUT * CIN) / 256), dim3(256), 0, stream, w);
  hipLaunchKernelGGL(aprconv, dim3(N_PTS / 64), dim3(256), 0, stream, nbr, lv, dlt, bias, out);
}